// Round 6
// baseline (98.868 us; speedup 1.0000x reference)
//
#include <hip/hip_runtime.h>
#include <math.h>

#define N 4096

// ---------------------------------------------------------------------------
// K1: LDS-staged stable descending rank by counting.
// grid 256x256: blocks 0..127 -> row A (32 elems each), 128..255 -> row B.
//   pos_i = #{j : x_j > x_i} + #{j<i : x_j == x_i}   (== stable argsort(-x))
//   scatter s[pos_i] = x_i  (descending sorted array)
// Row staged once in LDS: global traffic 134MB -> 4MB. Stripe-rotated LDS
// reads (base + ((c+s)&127)) put the 8 stripes in 8 distinct bank groups.
// ---------------------------------------------------------------------------
__global__ __launch_bounds__(256) void rank_kernel(
        const float* __restrict__ yh, const float* __restrict__ yv,
        float* __restrict__ sA, float* __restrict__ sB,
        int* __restrict__ posA, int* __restrict__ posB) {
    __shared__ float row_lds[N];               // 16 KB
    const int b = blockIdx.x;
    const int row = b >> 7;
    const float* X = row ? yv : yh;
    float4* L4 = (float4*)row_lds;
    const float4* X4 = (const float4*)X;
#pragma unroll
    for (int q = 0; q < 4; ++q)
        L4[q * 256 + threadIdx.x] = X4[q * 256 + threadIdx.x];
    __syncthreads();

    const int t  = threadIdx.x;
    const int el = t >> 3;                     // 0..31 element within block
    const int s  = t & 7;                      // stripe
    const int i  = (b & 127) * 32 + el;        // element index in row
    const float x = row_lds[i];
    int cnt = 0;
    const int base = s * 128;                  // 128 float4 = 512 elems/stripe
#pragma unroll 8
    for (int c = 0; c < 128; ++c) {
        int cc = base + ((c + s) & 127);       // rotated: bank group (c+s)&7
        float4 f = L4[cc];
        int j = 4 * cc;
        cnt += (int)(f.x > x) | ((int)(f.x == x) & (int)((j + 0) < i));
        cnt += (int)(f.y > x) | ((int)(f.y == x) & (int)((j + 1) < i));
        cnt += (int)(f.z > x) | ((int)(f.z == x) & (int)((j + 2) < i));
        cnt += (int)(f.w > x) | ((int)(f.w == x) & (int)((j + 3) < i));
    }
    cnt += __shfl_xor(cnt, 1, 8);
    cnt += __shfl_xor(cnt, 2, 8);
    cnt += __shfl_xor(cnt, 4, 8);
    if (s == 0) {
        if (row) { posB[i] = cnt; sB[cnt] = x; }
        else     { posA[i] = cnt; sA[cnt] = x; }
    }
}

// ---------------------------------------------------------------------------
// K2: both rows concurrently (waves 0-7 row A, 8-15 row B).
// C = prefix(z), z_p = s_p - (N-p), registers only. Non-increasing isotonic
// fit = slopes of upper convex hull of (p, C_p); chord-pruned survivors ->
// tiny serial Graham per row. KEY: s[pos_i] == x_i exactly, so the ranked
// value in original order is r_i = x_i - dual(pos_i) - shift — no primal
// array / scatter / gather needed. Epilogue: hull-slope lookup per original
// index, Pearson + BCE in double, write scalar.
// ---------------------------------------------------------------------------
__global__ __launch_bounds__(1024) void finalize_kernel(
        const float* __restrict__ yh, const float* __restrict__ yv,
        const float* __restrict__ sA, const float* __restrict__ sB,
        const int* __restrict__ posA, const int* __restrict__ posB,
        float* __restrict__ out) {
    __shared__ double wtot[2][8];
    __shared__ double CNsh[2];
    __shared__ unsigned short survX[2][512];
    __shared__ double survY[2][512];
    __shared__ unsigned short gX[2][516];
    __shared__ double gY[2][516];
    __shared__ int survCnt[2];
    __shared__ int Hsh[2];
    __shared__ double wred[16][6];             // total ~22 KB

    const int tid  = threadIdx.x;
    const int lane = tid & 63;
    const int wave = tid >> 6;
    const int r    = tid >> 9;                 // 0: row A, 1: row B
    const int ht   = tid & 511;
    const int hw   = wave & 7;
    const int q0   = ht * 8;

    // epilogue loads issued early to hide global latency under scan/hull
    int4 pa4 = ((const int4*)posA)[tid];
    int4 pb4 = ((const int4*)posB)[tid];
    float4 xh = ((const float4*)yh)[tid];
    float4 yt = ((const float4*)yv)[tid];

    const float* S = r ? sB : sA;
    float4 sa4 = ((const float4*)S)[2 * ht];
    float4 sb4 = ((const float4*)S)[2 * ht + 1];
    float sv[8] = {sa4.x, sa4.y, sa4.z, sa4.w, sb4.x, sb4.y, sb4.z, sb4.w};

    // ---- per-thread running prefix of z over 8 elements (registers) ----
    double m[8];
    double acc = 0.0;
#pragma unroll
    for (int j = 0; j < 8; ++j) {
        acc += (double)sv[j] - (double)(N - (q0 + j));
        m[j] = acc;
    }
    double tot = m[7], incl = tot;
#pragma unroll
    for (int d = 1; d < 64; d <<= 1) {
        double t = __shfl_up(incl, d, 64);
        if (lane >= d) incl += t;
    }
    if (lane == 63) wtot[r][hw] = incl;
    if (tid < 2) survCnt[tid] = 0;
    __syncthreads();                           // B0

    if (tid < 16) {
        int rr = tid >> 3, idx = tid & 7;
        double v = wtot[rr][idx], inc = v;
#pragma unroll
        for (int d = 1; d < 8; d <<= 1) {
            double t = __shfl_up(inc, d, 8);
            if (idx >= d) inc += t;
        }
        wtot[rr][idx] = inc - v;               // exclusive
        if (idx == 7) CNsh[rr] = inc;          // grand total = C_N
    }
    __syncthreads();                           // B1

    double base = wtot[r][hw] + (incl - tot);
    double CN = CNsh[r];
    double eps = 1e-9 * fabs(CN) + 1e-6;
    const double invN = 1.0 / (double)N;

    // ---- chord prune: C_p = base + m[j], all registers ----
#pragma unroll
    for (int j = 0; j < 8; ++j) {
        int p = q0 + 1 + j;
        if (p < N) {
            double cp = base + m[j];
            if (cp > CN * ((double)p * invN) - eps) {
                int slot = atomicAdd(&survCnt[r], 1);
                if (slot < 512) { survX[r][slot] = (unsigned short)p; survY[r][slot] = cp; }
            }
        }
    }
    __syncthreads();                           // B2

    // ---- serial per row: sort survivors, Graham upper hull (k ~ 0) ----
    if (ht == 0) {                             // tid 0 (row A) and tid 512 (row B)
        int k = survCnt[r]; if (k > 512) k = 512;
        for (int a = 1; a < k; ++a) {
            unsigned short vx = survX[r][a]; double vy = survY[r][a];
            int b = a - 1;
            while (b >= 0 && survX[r][b] > vx) {
                survX[r][b + 1] = survX[r][b]; survY[r][b + 1] = survY[r][b]; --b;
            }
            survX[r][b + 1] = vx; survY[r][b + 1] = vy;
        }
        int cnt = 0;
        int xa = 0, xb = 0; double ya = 0.0, yb = 0.0;
        for (int q = 0; q <= k + 1; ++q) {
            int x; double cy;
            if (q == 0)      { x = 0; cy = 0.0; }
            else if (q <= k) { x = (int)survX[r][q - 1]; cy = survY[r][q - 1]; }
            else             { x = N; cy = CN; }
            while (cnt >= 2) {
                double cr = (double)(xb - xa) * (cy - ya) - (yb - ya) * (double)(x - xa);
                if (cr >= 0.0) {
                    cnt--; xb = xa; yb = ya;
                    if (cnt >= 2) { xa = (int)gX[r][cnt - 2]; ya = gY[r][cnt - 2]; }
                } else break;
            }
            gX[r][cnt] = (unsigned short)x; gY[r][cnt] = cy;
            xa = xb; ya = yb; xb = x; yb = cy;
            cnt++;
        }
        Hsh[r] = cnt;
    }
    __syncthreads();                           // B3

    // ---- epilogue: r_i = x_i - dual(pos_i) - 2048; moments + BCE ----
    double Sa = 0, Sb = 0, Saa = 0, Sbb = 0, Sab = 0, Bce = 0;
    {
        int HA = Hsh[0], HB = Hsh[1];
        int pa[4] = {pa4.x, pa4.y, pa4.z, pa4.w};
        int pb[4] = {pb4.x, pb4.y, pb4.z, pb4.w};
        float xx[4] = {xh.x, xh.y, xh.z, xh.w};
        float yy[4] = {yt.x, yt.y, yt.z, yt.w};
#pragma unroll
        for (int j = 0; j < 4; ++j) {
            // row A dual lookup
            int p = pa[j];
            int a = 0, b2 = HA - 1;
            while (b2 - a > 1) {
                int mm = (a + b2) >> 1;
                if ((int)gX[0][mm] <= p) a = mm; else b2 = mm;
            }
            double dualA = (gY[0][b2] - gY[0][a]) / (double)((int)gX[0][b2] - (int)gX[0][a]);
            // row B dual lookup
            p = pb[j];
            a = 0; b2 = HB - 1;
            while (b2 - a > 1) {
                int mm = (a + b2) >> 1;
                if ((int)gX[1][mm] <= p) a = mm; else b2 = mm;
            }
            double dualB = (gY[1][b2] - gY[1][a]) / (double)((int)gX[1][b2] - (int)gX[1][a]);

            double av = (double)xx[j] - dualA - 2048.0;
            double bv = (double)yy[j] - dualB - 2048.0;
            Sa += av; Sb += bv; Saa += av * av; Sbb += bv * bv; Sab += av * bv;
            float x = xx[j];
            float e = __expf(-fabsf(x));           // (0,1] -> log arg in [1,2]
            float bt = fmaxf(x, 0.0f) + __logf(1.0f + e) - x * yy[j];
            Bce += (double)bt;
        }
    }
#pragma unroll
    for (int d = 32; d; d >>= 1) {
        Sa  += __shfl_xor(Sa, d, 64);  Sb  += __shfl_xor(Sb, d, 64);
        Saa += __shfl_xor(Saa, d, 64); Sbb += __shfl_xor(Sbb, d, 64);
        Sab += __shfl_xor(Sab, d, 64); Bce += __shfl_xor(Bce, d, 64);
    }
    if (lane == 0) {
        wred[wave][0] = Sa;  wred[wave][1] = Sb;  wred[wave][2] = Saa;
        wred[wave][3] = Sbb; wred[wave][4] = Sab; wred[wave][5] = Bce;
    }
    __syncthreads();                           // B4
    if (tid == 0) {
        double sa = 0, sb = 0, saa = 0, sbb = 0, sab = 0, bce = 0;
        for (int w = 0; w < 16; ++w) {
            sa += wred[w][0]; sb += wred[w][1]; saa += wred[w][2];
            sbb += wred[w][3]; sab += wred[w][4]; bce += wred[w][5];
        }
        double n = (double)N;
        double cov = sab - sa * sb / n;
        double va = saa - sa * sa / n;
        double vb = sbb - sb * sb / n;
        double spearman = cov / sqrt(va * vb);
        out[0] = (float)(1.0 - spearman + bce / n);
    }
}

extern "C" void kernel_launch(void* const* d_in, const int* in_sizes, int n_in,
                              void* d_out, int out_size, void* d_ws, size_t ws_size,
                              hipStream_t stream) {
    const float* yh = (const float*)d_in[0];
    const float* yv = (const float*)d_in[1];
    float* out = (float*)d_out;

    // workspace layout: sA, sB (desc-sorted), posA, posB
    float* sA  = (float*)d_ws;
    float* sB  = sA + N;
    int* posA  = (int*)(sB + N);
    int* posB  = posA + N;

    hipLaunchKernelGGL(rank_kernel, dim3(256), dim3(256), 0, stream,
                       yh, yv, sA, sB, posA, posB);
    hipLaunchKernelGGL(finalize_kernel, dim3(1), dim3(1024), 0, stream,
                       yh, yv, sA, sB, posA, posB, out);
}

// Round 7
// 77.462 us; speedup vs baseline: 1.2763x; 1.2763x over previous
//
#include <hip/hip_runtime.h>
#include <math.h>

#define N 4096

// ---------------------------------------------------------------------------
// K1 (exact R3 kernel — best measured): stable descending rank by counting.
// 8 lanes per element, 2 rows. Rows are L1-resident (16 KB each, 1 block/CU).
//   pos_i = #{j : x_j > x_i} + #{j<i : x_j == x_i}   (== stable argsort(-x))
//   scatter s[pos_i] = x_i  (descending sorted array)
// ---------------------------------------------------------------------------
__global__ __launch_bounds__(256) void rank_kernel(
        const float* __restrict__ yh, const float* __restrict__ yv,
        float* __restrict__ sA, float* __restrict__ sB,
        int* __restrict__ posA, int* __restrict__ posB) {
    int g = blockIdx.x * 256 + threadIdx.x;   // 0..65535
    int elem = g >> 3;                        // 0..8191
    int k = g & 7;                            // stripe
    int row = elem >> 12;
    int i = elem & (N - 1);
    const float* X = row ? yv : yh;
    float x = X[i];
    const float4* X4 = (const float4*)X;
    int cnt = 0;
    int m0 = k * 128;                         // 128 float4 = 512 elements per stripe
#pragma unroll 4
    for (int m = m0; m < m0 + 128; ++m) {
        float4 f = X4[m];
        int j = 4 * m;
        cnt += (int)(f.x > x) | ((int)(f.x == x) & (int)((j + 0) < i));
        cnt += (int)(f.y > x) | ((int)(f.y == x) & (int)((j + 1) < i));
        cnt += (int)(f.z > x) | ((int)(f.z == x) & (int)((j + 2) < i));
        cnt += (int)(f.w > x) | ((int)(f.w == x) & (int)((j + 3) < i));
    }
    cnt += __shfl_xor(cnt, 1, 8);
    cnt += __shfl_xor(cnt, 2, 8);
    cnt += __shfl_xor(cnt, 4, 8);
    if (k == 0) {
        if (row) { posB[i] = cnt; sB[cnt] = x; }
        else     { posA[i] = cnt; sA[cnt] = x; }
    }
}

// ---------------------------------------------------------------------------
// K2: both rows concurrently (waves 0-7 row A, 8-15 row B).
// C = prefix(z), z_p = s_p - (N-p), registers only. Non-increasing isotonic
// fit = slopes of upper convex hull of (p, C_p); chord-pruned survivors ->
// tiny serial Graham per row; segment slopes PRECOMPUTED once (H-1 ~ 1
// divide). s[pos_i] == x_i exactly, so the ranked value in original order is
// r_i = x_i - slope(seg(pos_i)) - shift — no primal array / scatter / gather.
// Epilogue: slope lookup per original index, Pearson + BCE in double.
// ---------------------------------------------------------------------------
__global__ __launch_bounds__(1024) void finalize_kernel(
        const float* __restrict__ yh, const float* __restrict__ yv,
        const float* __restrict__ sA, const float* __restrict__ sB,
        const int* __restrict__ posA, const int* __restrict__ posB,
        float* __restrict__ out) {
    __shared__ double wtot[2][8];
    __shared__ double CNsh[2];
    __shared__ unsigned short survX[2][512];
    __shared__ double survY[2][512];
    __shared__ unsigned short gX[2][516];
    __shared__ double gY[2][516];
    __shared__ double gSlope[2][516];
    __shared__ int survCnt[2];
    __shared__ int Hsh[2];
    __shared__ double wred[16][6];             // total ~30 KB

    const int tid  = threadIdx.x;
    const int lane = tid & 63;
    const int wave = tid >> 6;
    const int r    = tid >> 9;                 // 0: row A, 1: row B
    const int ht   = tid & 511;
    const int hw   = wave & 7;
    const int q0   = ht * 8;

    // epilogue loads issued early to hide global latency under scan/hull
    int4 pa4 = ((const int4*)posA)[tid];
    int4 pb4 = ((const int4*)posB)[tid];
    float4 xh = ((const float4*)yh)[tid];
    float4 yt = ((const float4*)yv)[tid];

    const float* S = r ? sB : sA;
    float4 sa4 = ((const float4*)S)[2 * ht];
    float4 sb4 = ((const float4*)S)[2 * ht + 1];
    float sv[8] = {sa4.x, sa4.y, sa4.z, sa4.w, sb4.x, sb4.y, sb4.z, sb4.w};

    // ---- per-thread running prefix of z over 8 elements (registers) ----
    double m[8];
    double acc = 0.0;
#pragma unroll
    for (int j = 0; j < 8; ++j) {
        acc += (double)sv[j] - (double)(N - (q0 + j));
        m[j] = acc;
    }
    double tot = m[7], incl = tot;
#pragma unroll
    for (int d = 1; d < 64; d <<= 1) {
        double t = __shfl_up(incl, d, 64);
        if (lane >= d) incl += t;
    }
    if (lane == 63) wtot[r][hw] = incl;
    if (tid < 2) survCnt[tid] = 0;
    __syncthreads();                           // B0

    if (tid < 16) {
        int rr = tid >> 3, idx = tid & 7;
        double v = wtot[rr][idx], inc = v;
#pragma unroll
        for (int d = 1; d < 8; d <<= 1) {
            double t = __shfl_up(inc, d, 8);
            if (idx >= d) inc += t;
        }
        wtot[rr][idx] = inc - v;               // exclusive
        if (idx == 7) CNsh[rr] = inc;          // grand total = C_N
    }
    __syncthreads();                           // B1

    double base = wtot[r][hw] + (incl - tot);
    double CN = CNsh[r];
    double eps = 1e-9 * fabs(CN) + 1e-6;
    const double invN = 1.0 / (double)N;

    // ---- chord prune: C_p = base + m[j], all registers ----
#pragma unroll
    for (int j = 0; j < 8; ++j) {
        int p = q0 + 1 + j;
        if (p < N) {
            double cp = base + m[j];
            if (cp > CN * ((double)p * invN) - eps) {
                int slot = atomicAdd(&survCnt[r], 1);
                if (slot < 512) { survX[r][slot] = (unsigned short)p; survY[r][slot] = cp; }
            }
        }
    }
    __syncthreads();                           // B2

    // ---- serial per row: sort survivors, Graham upper hull, slopes ----
    if (ht == 0) {                             // tid 0 (row A) and tid 512 (row B)
        int k = survCnt[r]; if (k > 512) k = 512;
        for (int a = 1; a < k; ++a) {
            unsigned short vx = survX[r][a]; double vy = survY[r][a];
            int b = a - 1;
            while (b >= 0 && survX[r][b] > vx) {
                survX[r][b + 1] = survX[r][b]; survY[r][b + 1] = survY[r][b]; --b;
            }
            survX[r][b + 1] = vx; survY[r][b + 1] = vy;
        }
        int cnt = 0;
        int xa = 0, xb = 0; double ya = 0.0, yb = 0.0;
        for (int q = 0; q <= k + 1; ++q) {
            int x; double cy;
            if (q == 0)      { x = 0; cy = 0.0; }
            else if (q <= k) { x = (int)survX[r][q - 1]; cy = survY[r][q - 1]; }
            else             { x = N; cy = CN; }
            while (cnt >= 2) {
                double cr = (double)(xb - xa) * (cy - ya) - (yb - ya) * (double)(x - xa);
                if (cr >= 0.0) {
                    cnt--; xb = xa; yb = ya;
                    if (cnt >= 2) { xa = (int)gX[r][cnt - 2]; ya = gY[r][cnt - 2]; }
                } else break;
            }
            gX[r][cnt] = (unsigned short)x; gY[r][cnt] = cy;
            xa = xb; ya = yb; xb = x; yb = cy;
            cnt++;
        }
        Hsh[r] = cnt;
        for (int q = 0; q + 1 < cnt; ++q)      // expected cnt==2 -> 1 divide
            gSlope[r][q] = (gY[r][q + 1] - gY[r][q]) /
                           (double)((int)gX[r][q + 1] - (int)gX[r][q]);
    }
    __syncthreads();                           // B3

    // ---- epilogue: r_i = x_i - slope(seg(pos_i)) - 2048; moments + BCE ----
    double Sa = 0, Sb = 0, Saa = 0, Sbb = 0, Sab = 0, Bce = 0;
    {
        int HA = Hsh[0], HB = Hsh[1];
        int pa[4] = {pa4.x, pa4.y, pa4.z, pa4.w};
        int pb[4] = {pb4.x, pb4.y, pb4.z, pb4.w};
        float xx[4] = {xh.x, xh.y, xh.z, xh.w};
        float yy[4] = {yt.x, yt.y, yt.z, yt.w};
#pragma unroll
        for (int j = 0; j < 4; ++j) {
            int p = pa[j];
            int a = 0, b2 = HA - 1;
            while (b2 - a > 1) {               // H==2 -> loop skipped
                int mm = (a + b2) >> 1;
                if ((int)gX[0][mm] <= p) a = mm; else b2 = mm;
            }
            double dualA = gSlope[0][a];
            p = pb[j];
            a = 0; b2 = HB - 1;
            while (b2 - a > 1) {
                int mm = (a + b2) >> 1;
                if ((int)gX[1][mm] <= p) a = mm; else b2 = mm;
            }
            double dualB = gSlope[1][a];

            double av = (double)xx[j] - dualA - 2048.0;
            double bv = (double)yy[j] - dualB - 2048.0;
            Sa += av; Sb += bv; Saa += av * av; Sbb += bv * bv; Sab += av * bv;
            float x = xx[j];
            float e = __expf(-fabsf(x));           // (0,1] -> log arg in [1,2]
            float bt = fmaxf(x, 0.0f) + __logf(1.0f + e) - x * yy[j];
            Bce += (double)bt;
        }
    }
#pragma unroll
    for (int d = 32; d; d >>= 1) {
        Sa  += __shfl_xor(Sa, d, 64);  Sb  += __shfl_xor(Sb, d, 64);
        Saa += __shfl_xor(Saa, d, 64); Sbb += __shfl_xor(Sbb, d, 64);
        Sab += __shfl_xor(Sab, d, 64); Bce += __shfl_xor(Bce, d, 64);
    }
    if (lane == 0) {
        wred[wave][0] = Sa;  wred[wave][1] = Sb;  wred[wave][2] = Saa;
        wred[wave][3] = Sbb; wred[wave][4] = Sab; wred[wave][5] = Bce;
    }
    __syncthreads();                           // B4
    if (tid == 0) {
        double sa = 0, sb = 0, saa = 0, sbb = 0, sab = 0, bce = 0;
        for (int w = 0; w < 16; ++w) {
            sa += wred[w][0]; sb += wred[w][1]; saa += wred[w][2];
            sbb += wred[w][3]; sab += wred[w][4]; bce += wred[w][5];
        }
        double n = (double)N;
        double cov = sab - sa * sb / n;
        double va = saa - sa * sa / n;
        double vb = sbb - sb * sb / n;
        double spearman = cov / sqrt(va * vb);
        out[0] = (float)(1.0 - spearman + bce / n);
    }
}

extern "C" void kernel_launch(void* const* d_in, const int* in_sizes, int n_in,
                              void* d_out, int out_size, void* d_ws, size_t ws_size,
                              hipStream_t stream) {
    const float* yh = (const float*)d_in[0];
    const float* yv = (const float*)d_in[1];
    float* out = (float*)d_out;

    // workspace layout: sA, sB (desc-sorted), posA, posB
    float* sA  = (float*)d_ws;
    float* sB  = sA + N;
    int* posA  = (int*)(sB + N);
    int* posB  = posA + N;

    hipLaunchKernelGGL(rank_kernel, dim3(256), dim3(256), 0, stream,
                       yh, yv, sA, sB, posA, posB);
    hipLaunchKernelGGL(finalize_kernel, dim3(1), dim3(1024), 0, stream,
                       yh, yv, sA, sB, posA, posB, out);
}